// Round 5
// baseline (964.130 us; speedup 1.0000x reference)
//
#include <hip/hip_runtime.h>

// ---------------------------------------------------------------------------
// DeformableAttnBlock — round 5: full-dbuf gload_lds convs, 2-row waves,
// merged big-conv dispatch, bf16 warp gather.
// B=2, T=5, C=192, H=W=64, NH=4, NL=5, NP=4, DH=48
// ---------------------------------------------------------------------------

#define HWPX 4096
#define PPXN 4624      // 68*68
#define LQ   20480

typedef __attribute__((ext_vector_type(8))) short  short8;
typedef __attribute__((ext_vector_type(4))) short  short4v;
typedef __attribute__((ext_vector_type(4))) float  f32x4;

__device__ __forceinline__ unsigned short f2bf(float f) {
    unsigned u = __float_as_uint(f);
    unsigned r = (u + 0x7FFF + ((u >> 16) & 1)) >> 16;   // RNE
    return (unsigned short)r;
}
__device__ __forceinline__ float bf2f(unsigned short s) {
    return __uint_as_float(((unsigned)s) << 16);
}

__device__ __forceinline__ void gl_lds16(const unsigned short* g, unsigned short* l) {
    __builtin_amdgcn_global_load_lds(
        (const __attribute__((address_space(1))) unsigned int*)g,
        (__attribute__((address_space(3))) unsigned int*)l, 16, 0, 0);
}

// ---------------------------------------------------------------------------
// K1: flow composition. flows layout (B, 5, 2, HW)
__device__ __forceinline__ float bsample(const float* __restrict__ p, float sx, float sy) {
    sx = fminf(fmaxf(sx, 0.f), 63.f);
    sy = fminf(fmaxf(sy, 0.f), 63.f);
    float x0 = floorf(sx), y0 = floorf(sy);
    int ix0 = (int)x0, iy0 = (int)y0;
    int ix1 = ix0 < 63 ? ix0 + 1 : 63;
    int iy1 = iy0 < 63 ? iy0 + 1 : 63;
    float wx = sx - x0, wy = sy - y0;
    float v00 = p[iy0*64+ix0], v01 = p[iy0*64+ix1];
    float v10 = p[iy1*64+ix0], v11 = p[iy1*64+ix1];
    return (v00*(1.f-wx) + v01*wx)*(1.f-wy) + (v10*(1.f-wx) + v11*wx)*wy;
}

__global__ __launch_bounds__(256) void k_flow(const float* __restrict__ ff,
                                              const float* __restrict__ fb,
                                              float* __restrict__ flows) {
    int i = blockIdx.x*256 + threadIdx.x;
    int b = i >> 12, pix = i & 4095;
    int x = pix & 63, y = pix >> 6;
    const float* ff01 = ff + (size_t)(b*4+0)*2*HWPX;
    const float* ff12 = ff + (size_t)(b*4+1)*2*HWPX;
    const float* fb32 = fb + (size_t)(b*4+2)*2*HWPX;
    const float* fb43 = fb + (size_t)(b*4+3)*2*HWPX;
    float* F = flows + (size_t)b*5*2*HWPX;
    float ax = ff01[pix], ay = ff01[HWPX+pix];
    float sx = bsample(ff12,      (float)x+ax, (float)y+ay);
    float sy = bsample(ff12+HWPX, (float)x+ax, (float)y+ay);
    F[0*2*HWPX + pix]        = ax + sx;
    F[0*2*HWPX + HWPX + pix] = ay + sy;
    F[1*2*HWPX + pix]        = ff12[pix];
    F[1*2*HWPX + HWPX + pix] = ff12[HWPX+pix];
    F[2*2*HWPX + pix]        = 0.f;
    F[2*2*HWPX + HWPX + pix] = 0.f;
    F[3*2*HWPX + pix]        = fb32[pix];
    F[3*2*HWPX + HWPX + pix] = fb32[HWPX+pix];
    float bx = fb43[pix], by = fb43[HWPX+pix];
    float tx = bsample(fb32,      (float)x+bx, (float)y+by);
    float ty = bsample(fb32+HWPX, (float)x+bx, (float)y+by);
    F[4*2*HWPX + pix]        = bx + tx;
    F[4*2*HWPX + HWPX + pix] = by + ty;
}

// ---------------------------------------------------------------------------
// K2: fused qk_in assembly from bf16 token-major padded P_v.
// P_v [b][4624][960] (5 slots x 192ch). Output P_qk [b][4624][992].
__global__ void k_qkin(const unsigned short* __restrict__ Pv,
                       const float* __restrict__ ff, const float* __restrict__ fb,
                       const float* __restrict__ flows,
                       unsigned short* __restrict__ Pqk)
{
    int ppx = blockIdx.x*64 + threadIdx.x;
    if (ppx >= PPXN) return;
    int b = blockIdx.z;
    int c8 = (blockIdx.y*4 + threadIdx.y)*8;
    unsigned short* dst = Pqk + ((size_t)b*PPXN + ppx)*992 + c8;
    int py = ppx/68, pxc = ppx - py*68;
    short8 o = {};
    if (py >= 2 && py < 66 && pxc >= 2 && pxc < 66 && c8 < 976) {
        int y = py-2, x = pxc-2, pix = (y<<6)+x;
        if (c8 >= 960) {
            #pragma unroll
            for (int j = 0; j < 8; ++j) {
                int k = c8 - 960 + j;
                float v = (k < 8) ? ff[((size_t)b*8 + k)*HWPX + pix]
                                  : fb[((size_t)b*8 + k - 8)*HWPX + pix];
                o[j] = (short)f2bf(v);
            }
        } else {
            const unsigned short* Pvb = Pv + (size_t)b*PPXN*960;
            int slot = c8/192;
            if (slot == 2) {
                o = *(const short8*)(Pvb + (size_t)ppx*960 + c8);
            } else {
                const float* F = flows + ((size_t)(b*5 + slot)*2)*HWPX;
                float sx = fminf(fmaxf((float)x + F[pix], 0.f), 63.f);
                float sy = fminf(fmaxf((float)y + F[HWPX + pix], 0.f), 63.f);
                float x0 = floorf(sx), y0 = floorf(sy);
                int ix0 = (int)x0, iy0 = (int)y0;
                int ix1 = ix0 < 63 ? ix0+1 : 63, iy1 = iy0 < 63 ? iy0+1 : 63;
                float wx = sx - x0, wy = sy - y0;
                float w00 = (1.f-wx)*(1.f-wy), w01 = wx*(1.f-wy);
                float w10 = (1.f-wx)*wy,       w11 = wx*wy;
                short8 v00 = *(const short8*)(Pvb + ((size_t)((iy0+2)*68 + ix0+2))*960 + c8);
                short8 v01 = *(const short8*)(Pvb + ((size_t)((iy0+2)*68 + ix1+2))*960 + c8);
                short8 v10 = *(const short8*)(Pvb + ((size_t)((iy1+2)*68 + ix0+2))*960 + c8);
                short8 v11 = *(const short8*)(Pvb + ((size_t)((iy1+2)*68 + ix1+2))*960 + c8);
                #pragma unroll
                for (int j = 0; j < 8; ++j) {
                    float v = bf2f((unsigned short)v00[j])*w00 + bf2f((unsigned short)v01[j])*w01
                            + bf2f((unsigned short)v10[j])*w10 + bf2f((unsigned short)v11[j])*w11;
                    o[j] = (short)f2bf(v);
                }
            }
        }
    }
    *(short8*)dst = o;
}

// ---------------------------------------------------------------------------
// t_pad: fp32 channel-major -> padded token-major bf16 (+ zero borders).
__global__ void t_pad(const float* __restrict__ in, unsigned short* __restrict__ outb,
                      int CI, int PITCH, int COFF)
{
    int ppx = blockIdx.x*64 + threadIdx.x;
    if (ppx >= PPXN) return;
    int img = blockIdx.z;
    int c8 = (blockIdx.y*4 + threadIdx.y)*8;
    unsigned short* dst = outb + ((size_t)img*PPXN + ppx)*PITCH;
    int py = ppx/68, pxc = ppx - py*68;
    if (py < 2 || py >= 66 || pxc < 2 || pxc >= 66) {
        short8 z = {};
        *(short8*)(dst + c8) = z;
        if (COFF) *(short8*)(dst + COFF + c8) = z;
        return;
    }
    int pix = ((py-2)<<6) + (pxc-2);
    short8 o;
    #pragma unroll
    for (int j = 0; j < 8; ++j)
        o[j] = (short)f2bf(in[((size_t)img*CI + c8 + j)*HWPX + pix]);
    *(short8*)(dst + COFF + c8) = o;
}

// t_zb: zero the borders of a padded token-major bf16 buffer.
__global__ __launch_bounds__(256) void t_zb(unsigned short* __restrict__ buf, int PITCH) {
    int id = blockIdx.x*256 + threadIdx.x;
    int perpx = PITCH >> 3;
    int ppx = id / perpx, c8 = (id - ppx*perpx) * 8;
    if (ppx >= PPXN) return;
    int py = ppx/68, pxc = ppx - py*68;
    if (py >= 2 && py < 66 && pxc >= 2 && pxc < 66) return;
    short8 z = {};
    *(short8*)(buf + ((size_t)blockIdx.y*PPXN + ppx)*PITCH + c8) = z;
}

// ---------------------------------------------------------------------------
// t_wT: conv weights w[CO][CI][3][3] fp32 -> wT[cotile][kblk][tap][cig][co][8] bf16
__global__ __launch_bounds__(256) void t_wT(const float* __restrict__ w,
                                            unsigned short* __restrict__ wT,
                                            int CI, int NKB) {
    int cotile = blockIdx.x, kblk = blockIdx.y;
    int tid = threadIdx.x & 255;
    unsigned short* dst = wT + ((size_t)(cotile*NKB + kblk))*18432;
    #pragma unroll
    for (int it = 0; it < 9; ++it) {
        int idx = it*256 + tid;
        int tap = idx >> 8, sub = idx & 255;
        int cg = sub >> 6, co = sub & 63;
        int cog = cotile*64 + co;
        int ci0 = kblk*32 + cg*8;
        short8 v;
        #pragma unroll
        for (int j = 0; j < 8; ++j) {
            int ci = ci0 + j;
            v[j] = (ci < CI) ? (short)f2bf(w[((size_t)cog*CI + ci)*9 + tap]) : (short)0;
        }
        *(short8*)(dst + (size_t)idx*8) = v;
    }
}

// t_wg: GEMM weights (K=192) -> wg[cotile][kblk6][cig4][co64][8] bf16, optional 2-src
__global__ __launch_bounds__(256) void t_wg(const float* __restrict__ w1,
                                            const float* __restrict__ w2,
                                            unsigned short* __restrict__ wg,
                                            int co_split, int CO) {
    int cotile = blockIdx.x;
    int tid = threadIdx.x & 255;
    unsigned short* dst = wg + (size_t)cotile*12288;
    #pragma unroll
    for (int it = 0; it < 6; ++it) {
        int idx = it*256 + tid;
        int kblk = idx >> 8, sub = idx & 255;
        int cg = sub >> 6, co = sub & 63;
        int cog = cotile*64 + co;
        int ci0 = kblk*32 + cg*8;
        short8 v = {};
        if (cog < CO) {
            const float* row = (cog < co_split) ? w1 + (size_t)cog*192
                                                : w2 + (size_t)(cog - co_split)*192;
            #pragma unroll
            for (int j = 0; j < 8; ++j) v[j] = (short)f2bf(row[ci0 + j]);
        }
        *(short8*)(dst + (size_t)idx*8) = v;
    }
}

// ---------------------------------------------------------------------------
// k_conv: MFMA implicit-GEMM 3x3 conv, fully double-buffered via global_load_lds.
// Block 256 thr / 4 waves; wave tile = 64co x (ROWS rows x 64 px); mb=4, nb=4*ROWS.
// One barrier per K-step; stage(kb+1) issued before compute(kb) -> drain ~free.
// njobs=2: blockIdx.z = job*2 + img (merged big-conv dispatch).
// OMODE: 0 = bf16 tok unpadded out (leaky)
//        1 = fp32 ch out + res AND bf16 padded tok cols0-191 of 384-pitch
//        2 = bf16 padded tok out (leaky)
//        3 = fp32 ch out + res
template<int ROWS, int DIL, int OMODE>
__global__ __launch_bounds__(256) void k_conv(
    const unsigned short* __restrict__ P0, const unsigned short* __restrict__ P1,
    int CIP0, int CIP1, int NKB0, int NKB1,
    const unsigned short* __restrict__ wT0, const unsigned short* __restrict__ wT1,
    const float* __restrict__ bias0, const float* __restrict__ bias1,
    const float* __restrict__ res, float* __restrict__ outF,
    unsigned short* __restrict__ outB0, unsigned short* __restrict__ outB1,
    int njobs, int CO)
{
    constexpr int RR    = ROWS*4 + 2*DIL;
    constexpr int XP    = 64 + 2*DIL;
    constexpr int PLANE = RR*XP*16;            // bytes per ci-plane
    constexpr int NCH   = RR*XP*4;             // 16B chunks in x-tile
    constexpr int NXS   = (NCH + 255)/256;
    __shared__ unsigned char  s_x[2][4*PLANE];
    __shared__ unsigned short s_w[2][18432];

    int tid = threadIdx.x & 255;
    int cotile = blockIdx.x, ytile = blockIdx.y;
    int z = blockIdx.z;
    int sel = (njobs == 2) ? (z >> 1) : 0;
    int img = (njobs == 2) ? (z & 1)  : z;
    const unsigned short* P  = sel ? P1  : P0;
    const unsigned short* wT = sel ? wT1 : wT0;
    const float* bias        = sel ? bias1 : bias0;
    unsigned short* outB     = sel ? outB1 : outB0;
    int CIP = sel ? CIP1 : CIP0;
    int NKB = sel ? NKB1 : NKB0;

    int y0 = ytile * (ROWS*4);
    const unsigned short* Pi = P + (size_t)img*PPXN*CIP;
    int w = tid >> 6, lane = tid & 63, lm = lane & 15, cig = lane >> 4;

    // ---- staging helpers (all global_load_lds; LDS dest linear in li) ----
    auto stage_x = [&](int kb, int buf) {
        int k0 = kb*32;
        #pragma unroll
        for (int it = 0; it < NXS; ++it) {
            int li = it*256 + tid;
            if (li < NCH) {
                int p = li / (RR*XP), rem = li - p*(RR*XP);
                int r = rem / XP, c = rem - r*XP;
                gl_lds16(Pi + ((size_t)((y0 + 2 - DIL + r)*68 + c + 2 - DIL))*CIP + k0 + p*8,
                         (unsigned short*)&s_x[buf][li*16]);
            }
        }
    };
    auto stage_w = [&](int kb, int buf) {
        const unsigned short* ws = wT + ((size_t)(cotile*NKB + kb))*18432;
        #pragma unroll
        for (int it = 0; it < 9; ++it)
            gl_lds16(ws + (size_t)(it*256+tid)*8, &s_w[buf][(it*256+tid)*8]);
    };

    stage_x(0, 0); stage_w(0, 0);
    __syncthreads();

    f32x4 acc[4][ROWS*4] = {};
    int buf = 0;
    for (int kb = 0; kb < NKB; ++kb) {
        if (kb + 1 < NKB) { stage_x(kb+1, buf^1); stage_w(kb+1, buf^1); }
        #pragma unroll
        for (int t = 0; t < 9; ++t) {
            int ky = t/3, kx = t - ky*3;
            short8 A[4];
            #pragma unroll
            for (int mb = 0; mb < 4; ++mb)
                A[mb] = *(const short8*)&s_w[buf][((t*4 + cig)*64 + mb*16 + lm)*8];
            #pragma unroll
            for (int s = 0; s < ROWS; ++s) {
                short8 Bf[4];
                #pragma unroll
                for (int nc = 0; nc < 4; ++nc)
                    Bf[nc] = *(const short8*)&s_x[buf][cig*PLANE +
                               ((w*ROWS + s + ky*DIL)*XP + nc*16 + lm + kx*DIL)*16];
                #pragma unroll
                for (int mb = 0; mb < 4; ++mb)
                    #pragma unroll
                    for (int nc = 0; nc < 4; ++nc)
                        acc[mb][s*4+nc] = __builtin_amdgcn_mfma_f32_16x16x32_bf16(
                            A[mb], Bf[nc], acc[mb][s*4+nc], 0, 0, 0);
            }
        }
        __syncthreads();          // drains staged loads (issued pre-compute) + ds
        buf ^= 1;
    }

    // epilogue: D row = co (mb*16 + cig*4 + r), col = px (nc*16 + lm)
    #pragma unroll
    for (int mb = 0; mb < 4; ++mb) {
        int cob = cotile*64 + mb*16 + cig*4;
        #pragma unroll
        for (int s = 0; s < ROWS; ++s) {
            int y = y0 + w*ROWS + s;
            #pragma unroll
            for (int nc = 0; nc < 4; ++nc) {
                int x = nc*16 + lm;
                int px = (y<<6) + x;
                float vv[4];
                #pragma unroll
                for (int r = 0; r < 4; ++r) {
                    float v = acc[mb][s*4+nc][r] + bias[cob + r];
                    if (OMODE == 0 || OMODE == 2) v = v >= 0.f ? v : 0.1f*v;
                    if (OMODE == 1 || OMODE == 3)
                        v += res[((size_t)img*192 + cob + r)*HWPX + px];
                    vv[r] = v;
                }
                if (OMODE == 0) {
                    int it = cob/192, cc = cob - it*192;
                    short4v sv;
                    #pragma unroll
                    for (int r = 0; r < 4; ++r) sv[r] = (short)f2bf(vv[r]);
                    *(short4v*)(outB + (((size_t)(img*5 + it)*HWPX + px)*192 + cc)) = sv;
                } else if (OMODE == 1) {
                    #pragma unroll
                    for (int r = 0; r < 4; ++r)
                        outF[((size_t)img*192 + cob + r)*HWPX + px] = vv[r];
                    int ppx = ((px>>6)+2)*68 + (px&63) + 2;
                    short4v sv;
                    #pragma unroll
                    for (int r = 0; r < 4; ++r) sv[r] = (short)f2bf(vv[r]);
                    *(short4v*)(outB + ((size_t)img*PPXN + ppx)*384 + cob) = sv;
                } else if (OMODE == 2) {
                    int ppx = ((px>>6)+2)*68 + (px&63) + 2;
                    short4v sv;
                    #pragma unroll
                    for (int r = 0; r < 4; ++r) sv[r] = (short)f2bf(vv[r]);
                    *(short4v*)(outB + ((size_t)img*PPXN + ppx)*192 + cob) = sv;
                } else {
                    #pragma unroll
                    for (int r = 0; r < 4; ++r)
                        outF[((size_t)img*192 + cob + r)*HWPX + px] = vv[r];
                }
            }
        }
    }
}

// ---------------------------------------------------------------------------
// k_gemmm: bf16 MFMA GEMM, K=192. X: [img][4096][192] tok bf16. Tile 64co x 256px.
// GMODE 0: vproj -> vp bf16 [img][4][4096][48]
// GMODE 1: off/attn -> offs fp32 [b][160][LQ], aw fp32 [b][80][LQ]
// GMODE 2: outproj -> P_ff bf16 padded [img][4624][192]
template<int GMODE>
__global__ __launch_bounds__(256) void k_gemmm(
    const unsigned short* __restrict__ X, const unsigned short* __restrict__ WG,
    const float* __restrict__ b1, const float* __restrict__ b2,
    float* __restrict__ o1, float* __restrict__ o2, unsigned short* __restrict__ ob)
{
    __shared__ unsigned char  s_x[2][4*4096];  // planes [cig][256px][16B]
    __shared__ unsigned short s_w[12288];
    int tid = threadIdx.x & 255;
    int cotile = blockIdx.x, pxt = blockIdx.y, img = blockIdx.z;
    int px0 = pxt*256;
    const unsigned short* Xi = X + (size_t)img*HWPX*192;
    #pragma unroll
    for (int it = 0; it < 6; ++it)
        gl_lds16(WG + (size_t)cotile*12288 + (it*256+tid)*8, &s_w[(it*256+tid)*8]);
    short8 xr[4];
    #pragma unroll
    for (int it = 0; it < 4; ++it)
        xr[it] = *(const short8*)(Xi + (size_t)(px0 + tid)*192 + it*8);
    #pragma unroll
    for (int it = 0; it < 4; ++it)
        *(short8*)&s_x[0][it*4096 + tid*16] = xr[it];
    __syncthreads();
    int w = tid >> 6, lane = tid & 63, lm = lane & 15, cig = lane >> 4;
    f32x4 acc[4][4] = {};
    int xb = 0;
    for (int kb = 0; kb < 6; ++kb) {
        bool pf = (kb < 5);
        if (pf) {
            int k0 = (kb+1)*32;
            #pragma unroll
            for (int it = 0; it < 4; ++it)
                xr[it] = *(const short8*)(Xi + (size_t)(px0 + tid)*192 + k0 + it*8);
        }
        short8 A[4], Bf[4];
        #pragma unroll
        for (int nb = 0; nb < 4; ++nb)
            Bf[nb] = *(const short8*)&s_x[xb][cig*4096 + (w*64 + nb*16 + lm)*16];
        #pragma unroll
        for (int mb = 0; mb < 4; ++mb)
            A[mb] = *(const short8*)&s_w[((kb*4 + cig)*64 + mb*16 + lm)*8];
        #pragma unroll
        for (int mb = 0; mb < 4; ++mb)
            #pragma unroll
            for (int nb = 0; nb < 4; ++nb)
                acc[mb][nb] = __builtin_amdgcn_mfma_f32_16x16x32_bf16(
                    A[mb], Bf[nb], acc[mb][nb], 0, 0, 0);
        if (pf) {
            #pragma unroll
            for (int it = 0; it < 4; ++it)
                *(short8*)&s_x[xb^1][it*4096 + tid*16] = xr[it];
        }
        __syncthreads();
        xb ^= 1;
    }
    int b = img/5, t = img - b*5;
    #pragma unroll
    for (int mb = 0; mb < 4; ++mb) {
        int cob = cotile*64 + mb*16 + cig*4;
        if (GMODE == 1 && cob >= 240) continue;
        #pragma unroll
        for (int nb = 0; nb < 4; ++nb) {
            int px = px0 + w*64 + nb*16 + lm;
            float vv[4];
            #pragma unroll
            for (int r = 0; r < 4; ++r) {
                float bv;
                if (GMODE == 1) bv = (cob + r < 160) ? b1[cob+r] : b2[cob+r-160];
                else bv = b1[cob + r];
                vv[r] = acc[mb][nb][r] + bv;
            }
            if (GMODE == 0) {
                int h = cob/48, d = cob - h*48;
                short4v s;
                #pragma unroll
                for (int r = 0; r < 4; ++r) s[r] = (short)f2bf(vv[r]);
                *(short4v*)(ob + (((size_t)img*4 + h)*HWPX + px)*48 + d) = s;
            } else if (GMODE == 1) {
                #pragma unroll
                for (int r = 0; r < 4; ++r) {
                    int co = cob + r;
                    if (co < 160) o1[((size_t)b*160 + co)*LQ + t*HWPX + px] = vv[r];
                    else          o2[((size_t)b*80 + co-160)*LQ + t*HWPX + px] = vv[r];
                }
            } else {
                int ppx = ((px>>6)+2)*68 + (px&63) + 2;
                short4v s;
                #pragma unroll
                for (int r = 0; r < 4; ++r) s[r] = (short)f2bf(vv[r]);
                *(short4v*)(ob + ((size_t)img*PPXN + ppx)*192 + cob) = s;
            }
        }
    }
}

// ---------------------------------------------------------------------------
// K7: softmax over 20 values at stride LQ (aw: (B, 4*20, LQ))
__global__ __launch_bounds__(256) void k_softmax20(float* __restrict__ aw) {
    int i = blockIdx.x*256 + threadIdx.x;
    int lq = i % LQ;
    int bh = i / LQ;
    float* p = aw + (size_t)bh*20*LQ + lq;
    float e[20];
    float m = -1e30f;
    #pragma unroll
    for (int j = 0; j < 20; ++j) { e[j] = p[(size_t)j*LQ]; m = fmaxf(m, e[j]); }
    float s = 0.f;
    #pragma unroll
    for (int j = 0; j < 20; ++j) { e[j] = expf(e[j]-m); s += e[j]; }
    float inv = 1.f/s;
    #pragma unroll
    for (int j = 0; j < 20; ++j) p[(size_t)j*LQ] = e[j]*inv;
}

// ---------------------------------------------------------------------------
// K8: deformable sampling. vp bf16 [b][l][h][4096][48]; out acc_tok bf16 [b][LQ][192]
__device__ __forceinline__ void addtap(float* acc, const unsigned short* __restrict__ src, float w) {
    const short8* s8 = (const short8*)src;
    #pragma unroll
    for (int q = 0; q < 6; ++q) {
        short8 v = s8[q];
        #pragma unroll
        for (int j = 0; j < 8; ++j)
            acc[q*8+j] += w * bf2f((unsigned short)v[j]);
    }
}

__global__ __launch_bounds__(256) void k_sample(
    const unsigned short* __restrict__ vp, const float* __restrict__ offs,
    const float* __restrict__ aw, const float* __restrict__ flows,
    unsigned short* __restrict__ accout)
{
    int blk = blockIdx.x;
    int b = blk / 320, sub = blk - b*320;
    int h = threadIdx.x >> 6;
    int lq = sub*64 + (threadIdx.x & 63);
    int pix = lq & 4095;
    int x = pix & 63, y = pix >> 6;
    const float* offp = offs + ((size_t)b*160 + h*40)*LQ + lq;
    const float* awp  = aw   + ((size_t)b*80  + h*20)*LQ + lq;
    float acc[48];
    #pragma unroll
    for (int d = 0; d < 48; ++d) acc[d] = 0.f;

    for (int l = 0; l < 5; ++l) {
        float fx = flows[((size_t)(b*5+l)*2+0)*HWPX + pix];
        float fy = flows[((size_t)(b*5+l)*2+1)*HWPX + pix];
        const unsigned short* vpl = vp + ((size_t)(b*5+l)*4 + h)*HWPX*48;
        #pragma unroll
        for (int p = 0; p < 4; ++p) {
            int o = l*4 + p;
            float ox = offp[(size_t)(2*o)*LQ];
            float oy = offp[(size_t)(2*o+1)*LQ];
            float wv = awp[(size_t)o*LQ];
            float sx = (float)x + ox + fx;
            float sy = (float)y + oy + fy;
            float x0f = floorf(sx), y0f = floorf(sy);
            float wx = sx - x0f, wy = sy - y0f;
            int ix0 = (int)x0f, iy0 = (int)y0f;
            float w00 = wv*(1.f-wx)*(1.f-wy), w01 = wv*wx*(1.f-wy);
            float w10 = wv*(1.f-wx)*wy,       w11 = wv*wx*wy;
            bool vx0 = (ix0 >= 0)  && (ix0 <= 63);
            bool vx1 = (ix0 >= -1) && (ix0 <= 62);
            bool vy0 = (iy0 >= 0)  && (iy0 <= 63);
            bool vy1 = (iy0 >= -1) && (iy0 <= 62);
            if (vy0 && vx0) addtap(acc, vpl + (size_t)(iy0*64 + ix0)*48,       w00);
            if (vy0 && vx1) addtap(acc, vpl + (size_t)(iy0*64 + ix0 + 1)*48,   w01);
            if (vy1 && vx0) addtap(acc, vpl + (size_t)((iy0+1)*64 + ix0)*48,   w10);
            if (vy1 && vx1) addtap(acc, vpl + (size_t)((iy0+1)*64 + ix0+1)*48, w11);
        }
    }
    unsigned short* dst = accout + ((size_t)b*LQ + lq)*192 + h*48;
    #pragma unroll
    for (int q = 0; q < 6; ++q) {
        short8 s;
        #pragma unroll
        for (int j = 0; j < 8; ++j) s[j] = (short)f2bf(acc[q*8+j]);
        *(short8*)(dst + q*8) = s;
    }
}

// ---------------------------------------------------------------------------

extern "C" void kernel_launch(void* const* d_in, const int* in_sizes, int n_in,
                              void* d_out, int out_size, void* d_ws, size_t ws_size,
                              hipStream_t stream) {
    (void)in_sizes; (void)n_in; (void)out_size; (void)ws_size;
    const float* frame    = (const float*)d_in[0];
    const float* srcframe = (const float*)d_in[1];
    const float* flow_f   = (const float*)d_in[2];
    const float* flow_b   = (const float*)d_in[3];
    const float* w_qk  = (const float*)d_in[4];  const float* b_qk  = (const float*)d_in[5];
    const float* w_v   = (const float*)d_in[6];  const float* b_v   = (const float*)d_in[7];
    const float* w_vp  = (const float*)d_in[8];  const float* b_vp  = (const float*)d_in[9];
    const float* w_off = (const float*)d_in[10]; const float* b_off = (const float*)d_in[11];
    const float* w_at  = (const float*)d_in[12]; const float* b_at  = (const float*)d_in[13];
    const float* w_out = (const float*)d_in[14]; const float* b_out = (const float*)d_in[15];
    const float* w_ff  = (const float*)d_in[16]; const float* b_ff  = (const float*)d_in[17];
    const float* w_f1  = (const float*)d_in[18]; const float* b_f1  = (const float*)d_in[19];
    const float* w_f2  = (const float*)d_in[20]; const float* b_f2  = (const float*)d_in[21];
    float* out = (float*)d_out;
    char* W = (char*)d_ws;

    // ---- workspace layout (bytes), total 192,182,272 <= ws_size ----
    float*          flows  = (float*)(W + 0);                    // 327,680
    unsigned short* wT_qk  = (unsigned short*)(W + 327680);      // 17,141,760
    unsigned short* wT_v   = (unsigned short*)(W + 17469440);    // 16,588,800
    unsigned short* wT_ff  = (unsigned short*)(W + 327680);      //   663,552 (recycled)
    unsigned short* wT_f1  = (unsigned short*)(W + 991232);      // 1,327,104
    unsigned short* wT_f2  = (unsigned short*)(W + 2318336);     //   663,552
    unsigned short* wg_vp  = (unsigned short*)(W + 2981888);     //    73,728
    unsigned short* wg_oa  = (unsigned short*)(W + 3055616);     //    98,304
    unsigned short* wg_out = (unsigned short*)(W + 3153920);     //    73,728
    unsigned short* P_qk   = (unsigned short*)(W + 34058240);    // 18,348,032
    unsigned short* P_ff   = P_qk;                               // reuse
    unsigned short* P_v    = (unsigned short*)(W + 52406272);    // 17,756,160
    unsigned short* P_mid  = P_v;                                // reuse
    unsigned short* Q_tok  = (unsigned short*)(W + 70162432);    // 15,728,640
    unsigned short* acc_tok= Q_tok;                              // reuse
    unsigned short* V_tok  = (unsigned short*)(W + 85891072);    // 15,728,640
    unsigned short* P_ffn1 = V_tok;                              // reuse (V_tok+vp+pad)
    unsigned short* vp     = (unsigned short*)(W + 101619712);   // 15,728,640
    float*          offs   = (float*)(W + 121403392);            // 26,214,400
    float*          aw     = (float*)(W + 147617792);            // 13,107,200
    float*          out1   = (float*)(W + 160724992);            // 31,457,280

    dim3 bp(64, 4);

    // 1. flow composition
    k_flow<<<32, 256, 0, stream>>>(flow_f, flow_b, flows);
    // 2. big conv weight transforms
    t_wT<<<dim3(15,31), 256, 0, stream>>>(w_qk, wT_qk, 976, 31);
    t_wT<<<dim3(15,30), 256, 0, stream>>>(w_v,  wT_v,  960, 30);
    // 3. frame -> padded tok bf16 (conv_v input AND warp source)
    t_pad<<<dim3(73,30,2), bp, 0, stream>>>(frame, P_v, 960, 960, 0);
    // 4. fused qk_in assembly from bf16 P_v (warp + pad)
    k_qkin<<<dim3(73,31,2), bp, 0, stream>>>(P_v, flow_f, flow_b, flows, P_qk);
    // 5. merged big convs: z = {qk img0, qk img1, v img0, v img1}
    k_conv<2,1,0><<<dim3(15,8,4), 256, 0, stream>>>(
        P_qk, P_v, 992, 960, 31, 30, wT_qk, wT_v, b_qk, b_v,
        nullptr, nullptr, Q_tok, V_tok, 2, 960);
    // 6. small transforms (recycle wT_qk slot — safe after step 5)
    t_wT<<<dim3(3,6),  256, 0, stream>>>(w_ff, wT_ff, 192, 6);
    t_wT<<<dim3(3,12), 256, 0, stream>>>(w_f1, wT_f1, 384, 12);
    t_wT<<<dim3(3,6),  256, 0, stream>>>(w_f2, wT_f2, 192, 6);
    t_wg<<<3, 256, 0, stream>>>(w_vp,  nullptr, wg_vp, 192, 192);
    t_wg<<<4, 256, 0, stream>>>(w_off, w_at,    wg_oa, 160, 240);
    t_wg<<<3, 256, 0, stream>>>(w_out, nullptr, wg_out, 192, 192);
    // 7. zero borders of padded buffers built by epilogues
    t_zb<<<dim3(434,10), 256, 0, stream>>>(P_ff, 192);
    t_zb<<<dim3(434,10), 256, 0, stream>>>(P_mid, 192);
    // 8. v_proj GEMM -> vp bf16
    k_gemmm<0><<<dim3(3,16,10), 256, 0, stream>>>(V_tok, wg_vp, b_vp, nullptr,
                                                  nullptr, nullptr, vp);
    // 9. offsets + attn logits GEMM
    k_gemmm<1><<<dim3(4,16,10), 256, 0, stream>>>(Q_tok, wg_oa, b_off, b_at,
                                                  offs, aw, nullptr);
    // 10. softmax over 20
    k_softmax20<<<640, 256, 0, stream>>>(aw);
    // 11. deformable sampling -> acc_tok bf16
    k_sample<<<640, 256, 0, stream>>>(vp, offs, aw, flows, acc_tok);
    // 12. srcframe -> P_ffn1 cols 192..383 + all borders (after vp/V_tok dead)
    t_pad<<<dim3(73,6,10), bp, 0, stream>>>(srcframe, P_ffn1, 192, 384, 192);
    // 13. output projection -> P_ff (padded tok bf16 interior)
    k_gemmm<2><<<dim3(3,16,10), 256, 0, stream>>>(acc_tok, wg_out, b_out, nullptr,
                                                  nullptr, nullptr, P_ff);
    // 14. conv_ff + frame residual -> out1 fp32 AND P_ffn1 cols 0..191
    k_conv<1,1,1><<<dim3(3,16,10), 256, 0, stream>>>(
        P_ff, nullptr, 192, 0, 6, 0, wT_ff, nullptr, b_ff, nullptr,
        frame, out1, P_ffn1, nullptr, 1, 192);
    // 15. ffn1 (dilation 2, leaky) -> P_mid
    k_conv<1,2,2><<<dim3(3,16,10), 256, 0, stream>>>(
        P_ffn1, nullptr, 384, 0, 12, 0, wT_f1, nullptr, b_f1, nullptr,
        nullptr, nullptr, P_mid, nullptr, 1, 192);
    // 16. ffn2 + out1 residual -> d_out
    k_conv<1,1,3><<<dim3(3,16,10), 256, 0, stream>>>(
        P_mid, nullptr, 192, 0, 6, 0, wT_f2, nullptr, b_f2, nullptr,
        out1, out, nullptr, nullptr, 1, 192);
    // 17. second output = srcframe passthrough
    hipMemcpyAsync(out + (size_t)2*5*192*HWPX, srcframe,
                   (size_t)2*5*192*HWPX*sizeof(float),
                   hipMemcpyDeviceToDevice, stream);
}

// Round 6
// 871.323 us; speedup vs baseline: 1.1065x; 1.1065x over previous
//
#include <hip/hip_runtime.h>

// ---------------------------------------------------------------------------
// DeformableAttnBlock — round 6: ROWS=2 convs at 2 blocks/CU (x reg-prefetch +
// w gl_lds restage-in-gap), XCD-aware block swizzle, merged big-conv dispatch.
// B=2, T=5, C=192, H=W=64, NH=4, NL=5, NP=4, DH=48
// ---------------------------------------------------------------------------

#define HWPX 4096
#define PPXN 4624      // 68*68
#define LQ   20480

typedef __attribute__((ext_vector_type(8))) short  short8;
typedef __attribute__((ext_vector_type(4))) short  short4v;
typedef __attribute__((ext_vector_type(4))) float  f32x4;

__device__ __forceinline__ unsigned short f2bf(float f) {
    unsigned u = __float_as_uint(f);
    unsigned r = (u + 0x7FFF + ((u >> 16) & 1)) >> 16;   // RNE
    return (unsigned short)r;
}
__device__ __forceinline__ float bf2f(unsigned short s) {
    return __uint_as_float(((unsigned)s) << 16);
}

__device__ __forceinline__ void gl_lds16(const unsigned short* g, unsigned short* l) {
    __builtin_amdgcn_global_load_lds(
        (const __attribute__((address_space(1))) unsigned int*)g,
        (__attribute__((address_space(3))) unsigned int*)l, 16, 0, 0);
}

// ---------------------------------------------------------------------------
// K1: flow composition. flows layout (B, 5, 2, HW)
__device__ __forceinline__ float bsample(const float* __restrict__ p, float sx, float sy) {
    sx = fminf(fmaxf(sx, 0.f), 63.f);
    sy = fminf(fmaxf(sy, 0.f), 63.f);
    float x0 = floorf(sx), y0 = floorf(sy);
    int ix0 = (int)x0, iy0 = (int)y0;
    int ix1 = ix0 < 63 ? ix0 + 1 : 63;
    int iy1 = iy0 < 63 ? iy0 + 1 : 63;
    float wx = sx - x0, wy = sy - y0;
    float v00 = p[iy0*64+ix0], v01 = p[iy0*64+ix1];
    float v10 = p[iy1*64+ix0], v11 = p[iy1*64+ix1];
    return (v00*(1.f-wx) + v01*wx)*(1.f-wy) + (v10*(1.f-wx) + v11*wx)*wy;
}

__global__ __launch_bounds__(256) void k_flow(const float* __restrict__ ff,
                                              const float* __restrict__ fb,
                                              float* __restrict__ flows) {
    int i = blockIdx.x*256 + threadIdx.x;
    int b = i >> 12, pix = i & 4095;
    int x = pix & 63, y = pix >> 6;
    const float* ff01 = ff + (size_t)(b*4+0)*2*HWPX;
    const float* ff12 = ff + (size_t)(b*4+1)*2*HWPX;
    const float* fb32 = fb + (size_t)(b*4+2)*2*HWPX;
    const float* fb43 = fb + (size_t)(b*4+3)*2*HWPX;
    float* F = flows + (size_t)b*5*2*HWPX;
    float ax = ff01[pix], ay = ff01[HWPX+pix];
    float sx = bsample(ff12,      (float)x+ax, (float)y+ay);
    float sy = bsample(ff12+HWPX, (float)x+ax, (float)y+ay);
    F[0*2*HWPX + pix]        = ax + sx;
    F[0*2*HWPX + HWPX + pix] = ay + sy;
    F[1*2*HWPX + pix]        = ff12[pix];
    F[1*2*HWPX + HWPX + pix] = ff12[HWPX+pix];
    F[2*2*HWPX + pix]        = 0.f;
    F[2*2*HWPX + HWPX + pix] = 0.f;
    F[3*2*HWPX + pix]        = fb32[pix];
    F[3*2*HWPX + HWPX + pix] = fb32[HWPX+pix];
    float bx = fb43[pix], by = fb43[HWPX+pix];
    float tx = bsample(fb32,      (float)x+bx, (float)y+by);
    float ty = bsample(fb32+HWPX, (float)x+bx, (float)y+by);
    F[4*2*HWPX + pix]        = bx + tx;
    F[4*2*HWPX + HWPX + pix] = by + ty;
}

// ---------------------------------------------------------------------------
// K2: fused qk_in assembly from bf16 token-major padded P_v.
// P_v [b][4624][960] (5 slots x 192ch). Output P_qk [b][4624][992].
__global__ void k_qkin(const unsigned short* __restrict__ Pv,
                       const float* __restrict__ ff, const float* __restrict__ fb,
                       const float* __restrict__ flows,
                       unsigned short* __restrict__ Pqk)
{
    int ppx = blockIdx.x*64 + threadIdx.x;
    if (ppx >= PPXN) return;
    int b = blockIdx.z;
    int c8 = (blockIdx.y*4 + threadIdx.y)*8;
    unsigned short* dst = Pqk + ((size_t)b*PPXN + ppx)*992 + c8;
    int py = ppx/68, pxc = ppx - py*68;
    short8 o = {};
    if (py >= 2 && py < 66 && pxc >= 2 && pxc < 66 && c8 < 976) {
        int y = py-2, x = pxc-2, pix = (y<<6)+x;
        if (c8 >= 960) {
            #pragma unroll
            for (int j = 0; j < 8; ++j) {
                int k = c8 - 960 + j;
                float v = (k < 8) ? ff[((size_t)b*8 + k)*HWPX + pix]
                                  : fb[((size_t)b*8 + k - 8)*HWPX + pix];
                o[j] = (short)f2bf(v);
            }
        } else {
            const unsigned short* Pvb = Pv + (size_t)b*PPXN*960;
            int slot = c8/192;
            if (slot == 2) {
                o = *(const short8*)(Pvb + (size_t)ppx*960 + c8);
            } else {
                const float* F = flows + ((size_t)(b*5 + slot)*2)*HWPX;
                float sx = fminf(fmaxf((float)x + F[pix], 0.f), 63.f);
                float sy = fminf(fmaxf((float)y + F[HWPX + pix], 0.f), 63.f);
                float x0 = floorf(sx), y0 = floorf(sy);
                int ix0 = (int)x0, iy0 = (int)y0;
                int ix1 = ix0 < 63 ? ix0+1 : 63, iy1 = iy0 < 63 ? iy0+1 : 63;
                float wx = sx - x0, wy = sy - y0;
                float w00 = (1.f-wx)*(1.f-wy), w01 = wx*(1.f-wy);
                float w10 = (1.f-wx)*wy,       w11 = wx*wy;
                short8 v00 = *(const short8*)(Pvb + ((size_t)((iy0+2)*68 + ix0+2))*960 + c8);
                short8 v01 = *(const short8*)(Pvb + ((size_t)((iy0+2)*68 + ix1+2))*960 + c8);
                short8 v10 = *(const short8*)(Pvb + ((size_t)((iy1+2)*68 + ix0+2))*960 + c8);
                short8 v11 = *(const short8*)(Pvb + ((size_t)((iy1+2)*68 + ix1+2))*960 + c8);
                #pragma unroll
                for (int j = 0; j < 8; ++j) {
                    float v = bf2f((unsigned short)v00[j])*w00 + bf2f((unsigned short)v01[j])*w01
                            + bf2f((unsigned short)v10[j])*w10 + bf2f((unsigned short)v11[j])*w11;
                    o[j] = (short)f2bf(v);
                }
            }
        }
    }
    *(short8*)dst = o;
}

// ---------------------------------------------------------------------------
// t_pad: fp32 channel-major -> padded token-major bf16 (+ zero borders).
__global__ void t_pad(const float* __restrict__ in, unsigned short* __restrict__ outb,
                      int CI, int PITCH, int COFF)
{
    int ppx = blockIdx.x*64 + threadIdx.x;
    if (ppx >= PPXN) return;
    int img = blockIdx.z;
    int c8 = (blockIdx.y*4 + threadIdx.y)*8;
    unsigned short* dst = outb + ((size_t)img*PPXN + ppx)*PITCH;
    int py = ppx/68, pxc = ppx - py*68;
    if (py < 2 || py >= 66 || pxc < 2 || pxc >= 66) {
        short8 z = {};
        *(short8*)(dst + c8) = z;
        if (COFF) *(short8*)(dst + COFF + c8) = z;
        return;
    }
    int pix = ((py-2)<<6) + (pxc-2);
    short8 o;
    #pragma unroll
    for (int j = 0; j < 8; ++j)
        o[j] = (short)f2bf(in[((size_t)img*CI + c8 + j)*HWPX + pix]);
    *(short8*)(dst + COFF + c8) = o;
}

// t_zb: zero the borders of a padded token-major bf16 buffer.
__global__ __launch_bounds__(256) void t_zb(unsigned short* __restrict__ buf, int PITCH) {
    int id = blockIdx.x*256 + threadIdx.x;
    int perpx = PITCH >> 3;
    int ppx = id / perpx, c8 = (id - ppx*perpx) * 8;
    if (ppx >= PPXN) return;
    int py = ppx/68, pxc = ppx - py*68;
    if (py >= 2 && py < 66 && pxc >= 2 && pxc < 66) return;
    short8 z = {};
    *(short8*)(buf + ((size_t)blockIdx.y*PPXN + ppx)*PITCH + c8) = z;
}

// ---------------------------------------------------------------------------
// t_wT: conv weights w[CO][CI][3][3] fp32 -> wT[cotile][kblk][tap][cig][co][8] bf16
__global__ __launch_bounds__(256) void t_wT(const float* __restrict__ w,
                                            unsigned short* __restrict__ wT,
                                            int CI, int NKB) {
    int cotile = blockIdx.x, kblk = blockIdx.y;
    int tid = threadIdx.x & 255;
    unsigned short* dst = wT + ((size_t)(cotile*NKB + kblk))*18432;
    #pragma unroll
    for (int it = 0; it < 9; ++it) {
        int idx = it*256 + tid;
        int tap = idx >> 8, sub = idx & 255;
        int cg = sub >> 6, co = sub & 63;
        int cog = cotile*64 + co;
        int ci0 = kblk*32 + cg*8;
        short8 v;
        #pragma unroll
        for (int j = 0; j < 8; ++j) {
            int ci = ci0 + j;
            v[j] = (ci < CI) ? (short)f2bf(w[((size_t)cog*CI + ci)*9 + tap]) : (short)0;
        }
        *(short8*)(dst + (size_t)idx*8) = v;
    }
}

// t_wg: GEMM weights (K=192) -> wg[cotile][kblk6][cig4][co64][8] bf16, optional 2-src
__global__ __launch_bounds__(256) void t_wg(const float* __restrict__ w1,
                                            const float* __restrict__ w2,
                                            unsigned short* __restrict__ wg,
                                            int co_split, int CO) {
    int cotile = blockIdx.x;
    int tid = threadIdx.x & 255;
    unsigned short* dst = wg + (size_t)cotile*12288;
    #pragma unroll
    for (int it = 0; it < 6; ++it) {
        int idx = it*256 + tid;
        int kblk = idx >> 8, sub = idx & 255;
        int cg = sub >> 6, co = sub & 63;
        int cog = cotile*64 + co;
        int ci0 = kblk*32 + cg*8;
        short8 v = {};
        if (cog < CO) {
            const float* row = (cog < co_split) ? w1 + (size_t)cog*192
                                                : w2 + (size_t)(cog - co_split)*192;
            #pragma unroll
            for (int j = 0; j < 8; ++j) v[j] = (short)f2bf(row[ci0 + j]);
        }
        *(short8*)(dst + (size_t)idx*8) = v;
    }
}

// ---------------------------------------------------------------------------
// k_conv: MFMA implicit-GEMM 3x3 conv over padded token-major bf16 input.
// Block 256 thr / 4 waves; wave tile = 64co x (ROWS rows x 64 px).
// LDS: x single-buffered 4-plane (conflict-free), reg-prefetch of next K-step
//      issued BEFORE compute (T14); w single-buffered, restaged via
//      global_load_lds in the barrier gap. 2 barriers per K-step, 2 blocks/CU.
// XCD-aware swizzle: blocks sharing one x-tile land on one XCD's L2 (T1).
// OMODE: 0 = bf16 tok unpadded out (leaky)
//        1 = fp32 ch out + res AND bf16 padded tok cols0-191 of 384-pitch
//        2 = bf16 padded tok out (leaky)
//        3 = fp32 ch out + res
template<int ROWS, int DIL, int OMODE>
__global__ __launch_bounds__(256, 2) void k_conv(
    const unsigned short* __restrict__ P0, const unsigned short* __restrict__ P1,
    int CIP0, int CIP1, int NKB0, int NKB1,
    const unsigned short* __restrict__ wT0, const unsigned short* __restrict__ wT1,
    const float* __restrict__ bias0, const float* __restrict__ bias1,
    const float* __restrict__ res, float* __restrict__ outF,
    unsigned short* __restrict__ outB0, unsigned short* __restrict__ outB1,
    int njobs, int CO)
{
    constexpr int RR    = ROWS*4 + 2*DIL;
    constexpr int XP    = 64 + 2*DIL;
    constexpr int PLANE = RR*XP*16;            // bytes per ci-plane
    constexpr int NCH   = RR*XP*4;             // 16B chunks in x-tile
    constexpr int NXS   = (NCH + 255)/256;
    __shared__ unsigned char  s_x[4*PLANE];    // ROWS2/DIL1: 42,240 B
    __shared__ unsigned short s_w[18432];      // 36,864 B

    int tid = threadIdx.x & 255;
    // XCD-aware swizzle (bijective when total%8==0)
    int gx = gridDim.x, gy = gridDim.y, gz = gridDim.z;
    int lin = blockIdx.x + gx*(blockIdx.y + gy*blockIdx.z);
    int tot = gx*gy*gz;
    if ((tot & 7) == 0) { int q = tot >> 3; lin = (lin & 7)*q + (lin >> 3); }
    int cotile = lin % gx; int rem = lin / gx;
    int ytile = rem % gy;  int z = rem / gy;

    int sel = (njobs == 2) ? (z >> 1) : 0;
    int img = (njobs == 2) ? (z & 1)  : z;
    const unsigned short* P  = sel ? P1  : P0;
    const unsigned short* wT = sel ? wT1 : wT0;
    const float* bias        = sel ? bias1 : bias0;
    unsigned short* outB     = sel ? outB1 : outB0;
    int CIP = sel ? CIP1 : CIP0;
    int NKB = sel ? NKB1 : NKB0;

    int y0 = ytile * (ROWS*4);
    const unsigned short* Pi = P + (size_t)img*PPXN*CIP;
    int w = tid >> 6, lane = tid & 63, lm = lane & 15, cig = lane >> 4;

    short8 xr[NXS];
    auto load_x = [&](int kb) {
        int k0 = kb*32;
        #pragma unroll
        for (int it = 0; it < NXS; ++it) {
            int li = it*256 + tid;
            if (li < NCH) {
                int p = li / (RR*XP), rm = li - p*(RR*XP);
                int r = rm / XP, c = rm - r*XP;
                xr[it] = *(const short8*)(Pi +
                    ((size_t)((y0 + 2 - DIL + r)*68 + c + 2 - DIL))*CIP + k0 + p*8);
            }
        }
    };
    auto write_x = [&]() {
        #pragma unroll
        for (int it = 0; it < NXS; ++it) {
            int li = it*256 + tid;
            if (li < NCH) {
                int p = li / (RR*XP), rm = li - p*(RR*XP);
                *(short8*)&s_x[p*PLANE + rm*16] = xr[it];
            }
        }
    };
    auto stage_w = [&](int kb) {
        const unsigned short* ws = wT + ((size_t)(cotile*NKB + kb))*18432;
        #pragma unroll
        for (int it = 0; it < 9; ++it)
            gl_lds16(ws + (size_t)(it*256+tid)*8, &s_w[(it*256+tid)*8]);
    };

    // prologue
    load_x(0); stage_w(0); write_x();
    __syncthreads();

    f32x4 acc[4][ROWS*4] = {};
    for (int kb = 0; kb < NKB; ++kb) {
        bool pf = (kb + 1 < NKB);
        if (pf) load_x(kb+1);                 // global->reg, lands under compute
        #pragma unroll
        for (int t = 0; t < 9; ++t) {
            int ky = t/3, kx = t - ky*3;
            short8 A[4];
            #pragma unroll
            for (int mb = 0; mb < 4; ++mb)
                A[mb] = *(const short8*)&s_w[((t*4 + cig)*64 + mb*16 + lm)*8];
            #pragma unroll
            for (int s = 0; s < ROWS; ++s) {
                short8 Bf[4];
                #pragma unroll
                for (int nc = 0; nc < 4; ++nc)
                    Bf[nc] = *(const short8*)&s_x[cig*PLANE +
                               ((w*ROWS + s + ky*DIL)*XP + nc*16 + lm + kx*DIL)*16];
                #pragma unroll
                for (int mb = 0; mb < 4; ++mb)
                    #pragma unroll
                    for (int nc = 0; nc < 4; ++nc)
                        acc[mb][s*4+nc] = __builtin_amdgcn_mfma_f32_16x16x32_bf16(
                            A[mb], Bf[nc], acc[mb][s*4+nc], 0, 0, 0);
            }
        }
        __syncthreads();                      // all waves done reading s_x, s_w
        if (pf) { stage_w(kb+1); write_x(); }
        __syncthreads();                      // new x + w visible (drains vmcnt)
    }

    // epilogue: D row = co (mb*16 + cig*4 + r), col = px (nc*16 + lm)
    #pragma unroll
    for (int mb = 0; mb < 4; ++mb) {
        int cob = cotile*64 + mb*16 + cig*4;
        #pragma unroll
        for (int s = 0; s < ROWS; ++s) {
            int y = y0 + w*ROWS + s;
            #pragma unroll
            for (int nc = 0; nc < 4; ++nc) {
                int x = nc*16 + lm;
                int px = (y<<6) + x;
                float vv[4];
                #pragma unroll
                for (int r = 0; r < 4; ++r) {
                    float v = acc[mb][s*4+nc][r] + bias[cob + r];
                    if (OMODE == 0 || OMODE == 2) v = v >= 0.f ? v : 0.1f*v;
                    if (OMODE == 1 || OMODE == 3)
                        v += res[((size_t)img*192 + cob + r)*HWPX + px];
                    vv[r] = v;
                }
                if (OMODE == 0) {
                    int it = cob/192, cc = cob - it*192;
                    short4v sv;
                    #pragma unroll
                    for (int r = 0; r < 4; ++r) sv[r] = (short)f2bf(vv[r]);
                    *(short4v*)(outB + (((size_t)(img*5 + it)*HWPX + px)*192 + cc)) = sv;
                } else if (OMODE == 1) {
                    #pragma unroll
                    for (int r = 0; r < 4; ++r)
                        outF[((size_t)img*192 + cob + r)*HWPX + px] = vv[r];
                    int ppx = ((px>>6)+2)*68 + (px&63) + 2;
                    short4v sv;
                    #pragma unroll
                    for (int r = 0; r < 4; ++r) sv[r] = (short)f2bf(vv[r]);
                    *(short4v*)(outB + ((size_t)img*PPXN + ppx)*384 + cob) = sv;
                } else if (OMODE == 2) {
                    int ppx = ((px>>6)+2)*68 + (px&63) + 2;
                    short4v sv;
                    #pragma unroll
                    for (int r = 0; r < 4; ++r) sv[r] = (short)f2bf(vv[r]);
                    *(short4v*)(outB + ((size_t)img*PPXN + ppx)*192 + cob) = sv;
                } else {
                    #pragma unroll
                    for (int r = 0; r < 4; ++r)
                        outF[((size_t)img*192 + cob + r)*HWPX + px] = vv[r];
                }
            }
        }
    }
}

// ---------------------------------------------------------------------------
// k_gemmm: bf16 MFMA GEMM, K=192. X: [img][4096][192] tok bf16. Tile 64co x 256px.
// GMODE 0: vproj -> vp bf16 [img][4][4096][48]
// GMODE 1: off/attn -> offs fp32 [b][160][LQ], aw fp32 [b][80][LQ]
// GMODE 2: outproj -> P_ff bf16 padded [img][4624][192]
template<int GMODE>
__global__ __launch_bounds__(256) void k_gemmm(
    const unsigned short* __restrict__ X, const unsigned short* __restrict__ WG,
    const float* __restrict__ b1, const float* __restrict__ b2,
    float* __restrict__ o1, float* __restrict__ o2, unsigned short* __restrict__ ob)
{
    __shared__ unsigned char  s_x[2][4*4096];  // planes [cig][256px][16B]
    __shared__ unsigned short s_w[12288];
    int tid = threadIdx.x & 255;
    int cotile = blockIdx.x, pxt = blockIdx.y, img = blockIdx.z;
    int px0 = pxt*256;
    const unsigned short* Xi = X + (size_t)img*HWPX*192;
    #pragma unroll
    for (int it = 0; it < 6; ++it)
        gl_lds16(WG + (size_t)cotile*12288 + (it*256+tid)*8, &s_w[(it*256+tid)*8]);
    short8 xr[4];
    #pragma unroll
    for (int it = 0; it < 4; ++it)
        xr[it] = *(const short8*)(Xi + (size_t)(px0 + tid)*192 + it*8);
    #pragma unroll
    for (int it = 0; it < 4; ++it)
        *(short8*)&s_x[0][it*4096 + tid*16] = xr[it];
    __syncthreads();
    int w = tid >> 6, lane = tid & 63, lm = lane & 15, cig = lane >> 4;
    f32x4 acc[4][4] = {};
    int xb = 0;
    for (int kb = 0; kb < 6; ++kb) {
        bool pf = (kb < 5);
        if (pf) {
            int k0 = (kb+1)*32;
            #pragma unroll
            for (int it = 0; it < 4; ++it)
                xr[it] = *(const short8*)(Xi + (size_t)(px0 + tid)*192 + k0 + it*8);
        }
        short8 A[4], Bf[4];
        #pragma unroll
        for (int nb = 0; nb < 4; ++nb)
            Bf[nb] = *(const short8*)&s_x[xb][cig*4096 + (w*64 + nb*16 + lm)*16];
        #pragma unroll
        for (int mb = 0; mb < 4; ++mb)
            A[mb] = *(const short8*)&s_w[((kb*4 + cig)*64 + mb*16 + lm)*8];
        #pragma unroll
        for (int mb = 0; mb < 4; ++mb)
            #pragma unroll
            for (int nb = 0; nb < 4; ++nb)
                acc[mb][nb] = __builtin_amdgcn_mfma_f32_16x16x32_bf16(
                    A[mb], Bf[nb], acc[mb][nb], 0, 0, 0);
        if (pf) {
            #pragma unroll
            for (int it = 0; it < 4; ++it)
                *(short8*)&s_x[xb^1][it*4096 + tid*16] = xr[it];
        }
        __syncthreads();
        xb ^= 1;
    }
    int b = img/5, t = img - b*5;
    #pragma unroll
    for (int mb = 0; mb < 4; ++mb) {
        int cob = cotile*64 + mb*16 + cig*4;
        if (GMODE == 1 && cob >= 240) continue;
        #pragma unroll
        for (int nb = 0; nb < 4; ++nb) {
            int px = px0 + w*64 + nb*16 + lm;
            float vv[4];
            #pragma unroll
            for (int r = 0; r < 4; ++r) {
                float bv;
                if (GMODE == 1) bv = (cob + r < 160) ? b1[cob+r] : b2[cob+r-160];
                else bv = b1[cob + r];
                vv[r] = acc[mb][nb][r] + bv;
            }
            if (GMODE == 0) {
                int h = cob/48, d = cob - h*48;
                short4v s;
                #pragma unroll
                for (int r = 0; r < 4; ++r) s[r] = (short)f2bf(vv[r]);
                *(short4v*)(ob + (((size_t)img*4 + h)*HWPX + px)*48 + d) = s;
            } else if (GMODE == 1) {
                #pragma unroll
                for (int r = 0; r < 4; ++r) {
                    int co = cob + r;
                    if (co < 160) o1[((size_t)b*160 + co)*LQ + t*HWPX + px] = vv[r];
                    else          o2[((size_t)b*80 + co-160)*LQ + t*HWPX + px] = vv[r];
                }
            } else {
                int ppx = ((px>>6)+2)*68 + (px&63) + 2;
                short4v s;
                #pragma unroll
                for (int r = 0; r < 4; ++r) s[r] = (short)f2bf(vv[r]);
                *(short4v*)(ob + ((size_t)img*PPXN + ppx)*192 + cob) = s;
            }
        }
    }
}

// ---------------------------------------------------------------------------
// K7: softmax over 20 values at stride LQ (aw: (B, 4*20, LQ))
__global__ __launch_bounds__(256) void k_softmax20(float* __restrict__ aw) {
    int i = blockIdx.x*256 + threadIdx.x;
    int lq = i % LQ;
    int bh = i / LQ;
    float* p = aw + (size_t)bh*20*LQ + lq;
    float e[20];
    float m = -1e30f;
    #pragma unroll
    for (int j = 0; j < 20; ++j) { e[j] = p[(size_t)j*LQ]; m = fmaxf(m, e[j]); }
    float s = 0.f;
    #pragma unroll
    for (int j = 0; j < 20; ++j) { e[j] = expf(e[j]-m); s += e[j]; }
    float inv = 1.f/s;
    #pragma unroll
    for (int j = 0; j < 20; ++j) p[(size_t)j*LQ] = e[j]*inv;
}

// ---------------------------------------------------------------------------
// K8: deformable sampling. vp bf16 [b][l][h][4096][48]; out acc_tok bf16 [b][LQ][192]
__device__ __forceinline__ void addtap(float* acc, const unsigned short* __restrict__ src, float w) {
    const short8* s8 = (const short8*)src;
    #pragma unroll
    for (int q = 0; q < 6; ++q) {
        short8 v = s8[q];
        #pragma unroll
        for (int j = 0; j < 8; ++j)
            acc[q*8+j] += w * bf2f((unsigned short)v[j]);
    }
}

__global__ __launch_bounds__(256) void k_sample(
    const unsigned short* __restrict__ vp, const float* __restrict__ offs,
    const float* __restrict__ aw, const float* __restrict__ flows,
    unsigned short* __restrict__ accout)
{
    int blk = blockIdx.x;
    int b = blk / 320, sub = blk - b*320;
    int h = threadIdx.x >> 6;
    int lq = sub*64 + (threadIdx.x & 63);
    int pix = lq & 4095;
    int x = pix & 63, y = pix >> 6;
    const float* offp = offs + ((size_t)b*160 + h*40)*LQ + lq;
    const float* awp  = aw   + ((size_t)b*80  + h*20)*LQ + lq;
    float acc[48];
    #pragma unroll
    for (int d = 0; d < 48; ++d) acc[d] = 0.f;

    for (int l = 0; l < 5; ++l) {
        float fx = flows[((size_t)(b*5+l)*2+0)*HWPX + pix];
        float fy = flows[((size_t)(b*5+l)*2+1)*HWPX + pix];
        const unsigned short* vpl = vp + ((size_t)(b*5+l)*4 + h)*HWPX*48;
        #pragma unroll
        for (int p = 0; p < 4; ++p) {
            int o = l*4 + p;
            float ox = offp[(size_t)(2*o)*LQ];
            float oy = offp[(size_t)(2*o+1)*LQ];
            float wv = awp[(size_t)o*LQ];
            float sx = (float)x + ox + fx;
            float sy = (float)y + oy + fy;
            float x0f = floorf(sx), y0f = floorf(sy);
            float wx = sx - x0f, wy = sy - y0f;
            int ix0 = (int)x0f, iy0 = (int)y0f;
            float w00 = wv*(1.f-wx)*(1.f-wy), w01 = wv*wx*(1.f-wy);
            float w10 = wv*(1.f-wx)*wy,       w11 = wv*wx*wy;
            bool vx0 = (ix0 >= 0)  && (ix0 <= 63);
            bool vx1 = (ix0 >= -1) && (ix0 <= 62);
            bool vy0 = (iy0 >= 0)  && (iy0 <= 63);
            bool vy1 = (iy0 >= -1) && (iy0 <= 62);
            if (vy0 && vx0) addtap(acc, vpl + (size_t)(iy0*64 + ix0)*48,       w00);
            if (vy0 && vx1) addtap(acc, vpl + (size_t)(iy0*64 + ix0 + 1)*48,   w01);
            if (vy1 && vx0) addtap(acc, vpl + (size_t)((iy0+1)*64 + ix0)*48,   w10);
            if (vy1 && vx1) addtap(acc, vpl + (size_t)((iy0+1)*64 + ix0+1)*48, w11);
        }
    }
    unsigned short* dst = accout + ((size_t)b*LQ + lq)*192 + h*48;
    #pragma unroll
    for (int q = 0; q < 6; ++q) {
        short8 s;
        #pragma unroll
        for (int j = 0; j < 8; ++j) s[j] = (short)f2bf(acc[q*8+j]);
        *(short8*)(dst + q*8) = s;
    }
}

// ---------------------------------------------------------------------------

extern "C" void kernel_launch(void* const* d_in, const int* in_sizes, int n_in,
                              void* d_out, int out_size, void* d_ws, size_t ws_size,
                              hipStream_t stream) {
    (void)in_sizes; (void)n_in; (void)out_size; (void)ws_size;
    const float* frame    = (const float*)d_in[0];
    const float* srcframe = (const float*)d_in[1];
    const float* flow_f   = (const float*)d_in[2];
    const float* flow_b   = (const float*)d_in[3];
    const float* w_qk  = (const float*)d_in[4];  const float* b_qk  = (const float*)d_in[5];
    const float* w_v   = (const float*)d_in[6];  const float* b_v   = (const float*)d_in[7];
    const float* w_vp  = (const float*)d_in[8];  const float* b_vp  = (const float*)d_in[9];
    const float* w_off = (const float*)d_in[10]; const float* b_off = (const float*)d_in[11];
    const float* w_at  = (const float*)d_in[12]; const float* b_at  = (const float*)d_in[13];
    const float* w_out = (const float*)d_in[14]; const float* b_out = (const float*)d_in[15];
    const float* w_ff  = (const float*)d_in[16]; const float* b_ff  = (const float*)d_in[17];
    const float* w_f1  = (const float*)d_in[18]; const float* b_f1  = (const float*)d_in[19];
    const float* w_f2  = (const float*)d_in[20]; const float* b_f2  = (const float*)d_in[21];
    float* out = (float*)d_out;
    char* W = (char*)d_ws;

    // ---- workspace layout (bytes), total 192,182,272 <= ws_size ----
    float*          flows  = (float*)(W + 0);                    // 327,680
    unsigned short* wT_qk  = (unsigned short*)(W + 327680);      // 17,141,760
    unsigned short* wT_v   = (unsigned short*)(W + 17469440);    // 16,588,800
    unsigned short* wT_ff  = (unsigned short*)(W + 327680);      //   663,552 (recycled)
    unsigned short* wT_f1  = (unsigned short*)(W + 991232);      // 1,327,104
    unsigned short* wT_f2  = (unsigned short*)(W + 2318336);     //   663,552
    unsigned short* wg_vp  = (unsigned short*)(W + 2981888);     //    73,728
    unsigned short* wg_oa  = (unsigned short*)(W + 3055616);     //    98,304
    unsigned short* wg_out = (unsigned short*)(W + 3153920);     //    73,728
    unsigned short* P_qk   = (unsigned short*)(W + 34058240);    // 18,348,032
    unsigned short* P_ff   = P_qk;                               // reuse
    unsigned short* P_v    = (unsigned short*)(W + 52406272);    // 17,756,160
    unsigned short* P_mid  = P_v;                                // reuse
    unsigned short* Q_tok  = (unsigned short*)(W + 70162432);    // 15,728,640
    unsigned short* acc_tok= Q_tok;                              // reuse
    unsigned short* V_tok  = (unsigned short*)(W + 85891072);    // 15,728,640
    unsigned short* P_ffn1 = V_tok;                              // reuse (V_tok+vp+pad)
    unsigned short* vp     = (unsigned short*)(W + 101619712);   // 15,728,640
    float*          offs   = (float*)(W + 121403392);            // 26,214,400
    float*          aw     = (float*)(W + 147617792);            // 13,107,200
    float*          out1   = (float*)(W + 160724992);            // 31,457,280

    dim3 bp(64, 4);

    // 1. flow composition
    k_flow<<<32, 256, 0, stream>>>(flow_f, flow_b, flows);
    // 2. big conv weight transforms
    t_wT<<<dim3(15,31), 256, 0, stream>>>(w_qk, wT_qk, 976, 31);
    t_wT<<<dim3(15,30), 256, 0, stream>>>(w_v,  wT_v,  960, 30);
    // 3. frame -> padded tok bf16 (conv_v input AND warp source)
    t_pad<<<dim3(73,30,2), bp, 0, stream>>>(frame, P_v, 960, 960, 0);
    // 4. fused qk_in assembly from bf16 P_v (warp + pad)
    k_qkin<<<dim3(73,31,2), bp, 0, stream>>>(P_v, flow_f, flow_b, flows, P_qk);
    // 5. merged big convs: z = {qk img0, qk img1, v img0, v img1}
    k_conv<2,1,0><<<dim3(15,8,4), 256, 0, stream>>>(
        P_qk, P_v, 992, 960, 31, 30, wT_qk, wT_v, b_qk, b_v,
        nullptr, nullptr, Q_tok, V_tok, 2, 960);
    // 6. small transforms (recycle wT_qk slot — safe after step 5)
    t_wT<<<dim3(3,6),  256, 0, stream>>>(w_ff, wT_ff, 192, 6);
    t_wT<<<dim3(3,12), 256, 0, stream>>>(w_f1, wT_f1, 384, 12);
    t_wT<<<dim3(3,6),  256, 0, stream>>>(w_f2, wT_f2, 192, 6);
    t_wg<<<3, 256, 0, stream>>>(w_vp,  nullptr, wg_vp, 192, 192);
    t_wg<<<4, 256, 0, stream>>>(w_off, w_at,    wg_oa, 160, 240);
    t_wg<<<3, 256, 0, stream>>>(w_out, nullptr, wg_out, 192, 192);
    // 7. zero borders of padded buffers built by epilogues
    t_zb<<<dim3(434,10), 256, 0, stream>>>(P_ff, 192);
    t_zb<<<dim3(434,10), 256, 0, stream>>>(P_mid, 192);
    // 8. v_proj GEMM -> vp bf16
    k_gemmm<0><<<dim3(3,16,10), 256, 0, stream>>>(V_tok, wg_vp, b_vp, nullptr,
                                                  nullptr, nullptr, vp);
    // 9. offsets + attn logits GEMM
    k_gemmm<1><<<dim3(4,16,10), 256, 0, stream>>>(Q_tok, wg_oa, b_off, b_at,
                                                  offs, aw, nullptr);
    // 10. softmax over 20
    k_softmax20<<<640, 256, 0, stream>>>(aw);
    // 11. deformable sampling -> acc_tok bf16
    k_sample<<<640, 256, 0, stream>>>(vp, offs, aw, flows, acc_tok);
    // 12. srcframe -> P_ffn1 cols 192..383 + all borders (after vp/V_tok dead)
    t_pad<<<dim3(73,6,10), bp, 0, stream>>>(srcframe, P_ffn1, 192, 384, 192);
    // 13. output projection -> P_ff (padded tok bf16 interior)
    k_gemmm<2><<<dim3(3,16,10), 256, 0, stream>>>(acc_tok, wg_out, b_out, nullptr,
                                                  nullptr, nullptr, P_ff);
    // 14. conv_ff + frame residual -> out1 fp32 AND P_ffn1 cols 0..191
    k_conv<1,1,1><<<dim3(3,16,10), 256, 0, stream>>>(
        P_ff, nullptr, 192, 0, 6, 0, wT_ff, nullptr, b_ff, nullptr,
        frame, out1, P_ffn1, nullptr, 1, 192);
    // 15. ffn1 (dilation 2, leaky) -> P_mid
    k_conv<1,2,2><<<dim3(3,16,10), 256, 0, stream>>>(
        P_ffn1, nullptr, 384, 0, 12, 0, wT_f1, nullptr, b_f1, nullptr,
        nullptr, nullptr, P_mid, nullptr, 1, 192);
    // 16. ffn2 + out1 residual -> d_out
    k_conv<1,1,3><<<dim3(3,16,10), 256, 0, stream>>>(
        P_mid, nullptr, 192, 0, 6, 0, wT_f2, nullptr, b_f2, nullptr,
        out1, out, nullptr, nullptr, 1, 192);
    // 17. second output = srcframe passthrough
    hipMemcpyAsync(out + (size_t)2*5*192*HWPX, srcframe,
                   (size_t)2*5*192*HWPX*sizeof(float),
                   hipMemcpyDeviceToDevice, stream);
}